// Round 11
// baseline (76.459 us; speedup 1.0000x reference)
//
#include <hip/hip_runtime.h>

namespace {
constexpr int BATCH = 512;
constexpr int SEQL  = 512;
constexpr int HID   = 256;
constexpr int MORPH = 24;
constexpr float NEGV = -1.0e9f;
constexpr int NTHR  = 1024;
constexpr int NBLK  = 256;    // 1 block/CU; each block owns a balanced wl-pair
}

typedef float f4v __attribute__((ext_vector_type(4)));

__device__ __forceinline__ unsigned okey(float f) {
    unsigned u = __float_as_uint(f);
    return u ^ (unsigned)(((int)u >> 31) | 0x80000000);
}

// 256 blocks x 1024 thr. Each block: (1) redundantly rank wl in LDS (no extra
// launch), (2) process b = order[i] then b = order[511-i] (snake pair: sum of
// pair work ~ const 536 rows) with the round-8 single-b body.
extern "C" __global__ __launch_bounds__(NTHR, 8)
void morphseg_pair(const float* __restrict__ we,    // [B, L, H]
                   const int*   __restrict__ wlen,  // [B]
                   const int*   __restrict__ nmorph,// [B]
                   const float* __restrict__ Wv,    // [H]
                   const float* __restrict__ bias,  // [1]
                   float* __restrict__ out)         // menc [B*M*H] then bpm [B*L*M]
{
    const int tid  = threadIdx.x;
    const int lane = tid & 63;
    const int wave = tid >> 6;

    __shared__ int s_wl[BATCH];                      // 2 KB
    __shared__ int s_order[BATCH];                   // 2 KB
    __shared__ unsigned s_keys[SEQL];                // 2 KB
    __shared__ int s_hist[256];                      // 1 KB
    __shared__ int s_c2m[SEQL];                      // 2 KB
    __shared__ float s_acc[MORPH][HID];              // 24 KB
    __shared__ unsigned long long s_eqm[8], s_ind[8];
    __shared__ unsigned s_p, s_T;
    __shared__ int s_Kr, s_KrF, s_done;

    const float b0 = bias[0];
    const unsigned KEYNEG = okey(NEGV);

    // ---- in-block wl ranking (stable desc): order[r] = b
    if (tid < BATCH) s_wl[tid] = wlen[tid];
    __syncthreads();
    if (tid < BATCH) {
        const int my = s_wl[tid];
        int r = 0;
        for (int j = 0; j < BATCH; ++j) {
            const int wj = s_wl[j];                  // uniform LDS broadcast
            r += (int)(wj > my) | ((int)(wj == my) & (int)(j < tid));
        }
        s_order[r] = tid;
    }
    __syncthreads();

    for (int pi = 0; pi < 2; ++pi) {
        const int b = (pi == 0) ? s_order[blockIdx.x]
                                : s_order[BATCH - 1 - blockIdx.x];
        const int wl = s_wl[b];
        const int nm = nmorph[b];
        const int K  = nm - 1;
        const float* __restrict__ werow = we + (size_t)b * (SEQL * HID);

        // ---- init
        if (tid < SEQL) s_keys[tid] = KEYNEG;
        {
            float* af = &s_acc[0][0];
            for (int i2 = tid; i2 < MORPH * HID; i2 += NTHR) af[i2] = 0.0f;
        }
        if (tid == 0) { s_p = 0u; s_Kr = K; s_done = 0; }
        __syncthreads();

        // ---- Phase 1: keys. 4 rows per wave per iter; lane = 16*rg + hg.
        {
            const int hg = lane & 15;
            const int rg = lane >> 4;
            const float4* __restrict__ W4 = reinterpret_cast<const float4*>(Wv);
            const float4 w0 = W4[hg * 4 + 0], w1 = W4[hg * 4 + 1];
            const float4 w2 = W4[hg * 4 + 2], w3 = W4[hg * 4 + 3];
            const int nvalid = wl - 1;
            for (int l0 = wave * 4; l0 < nvalid; l0 += 64) {
                const int row = l0 + rg;
                if (row < nvalid) {                  // uniform per 16-lane group
                    const float4* __restrict__ rp =
                        reinterpret_cast<const float4*>(werow + (size_t)row * HID);
                    const float4 v0 = rp[hg * 4 + 0], v1 = rp[hg * 4 + 1];
                    const float4 v2 = rp[hg * 4 + 2], v3 = rp[hg * 4 + 3];
                    float d = v0.x * w0.x; d = fmaf(v0.y, w0.y, d);
                    d = fmaf(v0.z, w0.z, d); d = fmaf(v0.w, w0.w, d);
                    d = fmaf(v1.x, w1.x, d); d = fmaf(v1.y, w1.y, d);
                    d = fmaf(v1.z, w1.z, d); d = fmaf(v1.w, w1.w, d);
                    d = fmaf(v2.x, w2.x, d); d = fmaf(v2.y, w2.y, d);
                    d = fmaf(v2.z, w2.z, d); d = fmaf(v2.w, w2.w, d);
                    d = fmaf(v3.x, w3.x, d); d = fmaf(v3.y, w3.y, d);
                    d = fmaf(v3.z, w3.z, d); d = fmaf(v3.w, w3.w, d);
                    #pragma unroll
                    for (int off = 1; off < 16; off <<= 1)
                        d += __shfl_xor(d, off, 64);
                    if (hg == 0) s_keys[row] = okey(d + b0);
                }
            }
        }
        __syncthreads();

        // ---- Phase 2: radix select, MSB-first, early exit on exact boundary
        int done = 0;
        for (int pass = 0; pass < 4 && !done; ++pass) {
            const int shift = 24 - 8 * pass;
            if (tid < 256) s_hist[tid] = 0;
            __syncthreads();
            if (tid < SEQL) {
                const unsigned k = s_keys[tid];
                if (pass == 0 || (k >> (shift + 8)) == (s_p >> (shift + 8)))
                    atomicAdd(&s_hist[(k >> shift) & 255], 1);
            }
            __syncthreads();
            if (wave == 0) {
                const int v0 = lane * 4;
                const int h0 = s_hist[v0], h1 = s_hist[v0 + 1];
                const int h2 = s_hist[v0 + 2], h3 = s_hist[v0 + 3];
                const int local = h0 + h1 + h2 + h3;
                int T = local;
                #pragma unroll
                for (int off = 1; off < 64; off <<= 1) {
                    const int u = __shfl_down(T, off, 64);
                    if (lane + off < 64) T += u;
                }
                const int A  = T - local;
                const int S3 = A + h3, S2 = S3 + h2, S1 = S2 + h1, S0 = S1 + h0;
                const int Kr = s_Kr;
                const unsigned p = s_p;
                int v = -1, Sv = 0, Sv1 = 0;
                if (A  < Kr && Kr <= S3) { v = v0 + 3; Sv = S3; Sv1 = A;  }
                if (S3 < Kr && Kr <= S2) { v = v0 + 2; Sv = S2; Sv1 = S3; }
                if (S2 < Kr && Kr <= S1) { v = v0 + 1; Sv = S1; Sv1 = S2; }
                if (S1 < Kr && Kr <= S0) { v = v0 + 0; Sv = S0; Sv1 = S1; }
                if (v >= 0) {
                    const unsigned pv = p | ((unsigned)v << shift);
                    if (Sv == Kr)        { s_T = pv - 1u; s_KrF = 0;        s_done = 1; }
                    else if (shift == 0) { s_T = pv;      s_KrF = Kr - Sv1; s_done = 1; }
                    else                 { s_p = pv;      s_Kr = Kr - Sv1; }
                }
            }
            __syncthreads();
            done = s_done;
        }

        // ---- separator flags (stable ties) -> c2m
        const unsigned Tf = s_T;
        const int KrF = s_KrF;
        const unsigned k = (tid < SEQL) ? s_keys[tid] : 0u;
        const bool gt = (tid < SEQL) && (k > Tf);
        const bool eq = (tid < SEQL) && (k == Tf);
        const unsigned long long eb = __ballot(eq);
        if (lane == 0 && wave < 8) s_eqm[wave] = eb;
        __syncthreads();

        auto prefix8 = [&](const unsigned long long* w8, int pos) -> int {
            const int wi = pos >> 6;
            const unsigned long long lowmask = (1ull << (pos & 63)) - 1ull;
            int r = 0;
            #pragma unroll
            for (int q2 = 0; q2 < 8; ++q2) {
                const unsigned long long w = w8[q2];
                r += (q2 < wi) ? __popcll(w) : ((q2 == wi) ? __popcll(w & lowmask) : 0);
            }
            return r;
        };

        int f = 0;
        if (tid < SEQL) f = gt || (eq && prefix8(s_eqm, tid) < KrF);
        const unsigned long long fb = __ballot(f);
        if (lane == 0 && wave < 8) s_ind[wave] = fb;
        __syncthreads();
        if (tid < SEQL) s_c2m[tid] = prefix8(s_ind, tid);
        __syncthreads();

        // ---- Phase 3+4 concurrent on disjoint waves
        if (wave >= 12) {
            // bpm one-hot (4 waves = 256 threads), NT float4 stores
            const int sub = tid - 768;
            float* __restrict__ bpm = out + (size_t)BATCH * MORPH * HID + (size_t)b * (SEQL * MORPH);
            for (int v = sub; v < SEQL * MORPH / 4; v += 256) {
                const int l  = v / 6;
                const int qv = v - l * 6;
                const int c  = s_c2m[l];
                const int mb = qv * 4;
                const bool valid = (l < wl);
                f4v o;
                o.x = (valid && c == mb + 0 && mb + 0 < nm) ? 1.0f : 0.0f;
                o.y = (valid && c == mb + 1 && mb + 1 < nm) ? 1.0f : 0.0f;
                o.z = (valid && c == mb + 2 && mb + 2 < nm) ? 1.0f : 0.0f;
                o.w = (valid && c == mb + 3 && mb + 3 < nm) ? 1.0f : 0.0f;
                __builtin_nontemporal_store(o, reinterpret_cast<f4v*>(bpm) + v);
            }
        } else {
            // menc: 12 waves, contiguous row chunks, LDS-atomic flush on change
            const int start = (wave * wl) / 12;
            const int end   = ((wave + 1) * wl) / 12;
            float4 acc = {0.f, 0.f, 0.f, 0.f};
            int mcur = -1;
            for (int l = start; l < end; ++l) {
                const int mm = s_c2m[l];           // wave-uniform broadcast
                if (mm != mcur) {                  // wave-uniform branch
                    if (mcur >= 0) {
                        atomicAdd(&s_acc[mcur][lane * 4 + 0], acc.x);
                        atomicAdd(&s_acc[mcur][lane * 4 + 1], acc.y);
                        atomicAdd(&s_acc[mcur][lane * 4 + 2], acc.z);
                        atomicAdd(&s_acc[mcur][lane * 4 + 3], acc.w);
                        acc.x = acc.y = acc.z = acc.w = 0.f;
                    }
                    mcur = mm;
                }
                const float4 v = reinterpret_cast<const float4*>(werow + (size_t)l * HID)[lane];
                acc.x += v.x; acc.y += v.y; acc.z += v.z; acc.w += v.w;
            }
            if (mcur >= 0) {
                atomicAdd(&s_acc[mcur][lane * 4 + 0], acc.x);
                atomicAdd(&s_acc[mcur][lane * 4 + 1], acc.y);
                atomicAdd(&s_acc[mcur][lane * 4 + 2], acc.z);
                atomicAdd(&s_acc[mcur][lane * 4 + 3], acc.w);
            }
        }
        __syncthreads();

        // ---- write menc (NT float4)
        {
            float* __restrict__ mout = out + (size_t)b * (MORPH * HID);
            const f4v* af = reinterpret_cast<const f4v*>(&s_acc[0][0]);
            for (int i2 = tid; i2 < MORPH * HID / 4; i2 += NTHR)
                __builtin_nontemporal_store(af[i2], reinterpret_cast<f4v*>(mout) + i2);
        }
        __syncthreads();   // protect s_acc/s_keys before next pair iteration
    }
}

extern "C" void kernel_launch(void* const* d_in, const int* in_sizes, int n_in,
                              void* d_out, int out_size, void* d_ws, size_t ws_size,
                              hipStream_t stream) {
    const float* we     = (const float*)d_in[0];
    const int*   wlen   = (const int*)d_in[1];
    const int*   nmorph = (const int*)d_in[2];
    const float* Wv     = (const float*)d_in[3];
    const float* bias   = (const float*)d_in[4];
    float* out = (float*)d_out;

    morphseg_pair<<<dim3(NBLK), dim3(NTHR), 0, stream>>>(
        we, wlen, nmorph, Wv, bias, out);
}